// Round 6
// baseline (328.590 us; speedup 1.0000x reference)
//
#include <hip/hip_runtime.h>

// AssociativeScanGateLoop: h_t = f_t*h_{t-1} + i_t*v_t per (b,d) sequence.
// x: (B=4, T=8192, 3*512) fp32.  out: (4, 8192, 512) fp32.
//
// Three-kernel chunked scan (v2.2):
//  K1  per-chunk affine aggregates (A, KV), float4-vectorized.
//  KS  O(C) exclusive scan over chunk aggregates -> h0 per chunk.
//  K2  seed h from h0, recompute chunk, write output (float4 + nontemporal).
//
// ws need: 3*B*C*DH*4 bytes (6 MiB at C=256); shrinks C if ws smaller;
// C==1 fallback uses no workspace at all.

#define B_  4
#define T_  8192
#define DH_ 512
#define ROW_ 1536

// clang ext-vector: __builtin_nontemporal_store requires this, not HIP float4.
typedef float f32x4 __attribute__((ext_vector_type(4)));

__device__ __forceinline__ float rcp_f(float x) {
    return __builtin_amdgcn_rcpf(x);   // v_rcp_f32, ~1 ulp — avoids div expansion
}
__device__ __forceinline__ float sigmoid_f(float x) {
    return rcp_f(1.0f + __expf(-x));
}
__device__ __forceinline__ float tanh_f(float x) {
    // 1 - 2/(e^{2x}+1): saturates to +/-1 even when __expf overflows to inf.
    return 1.0f - 2.0f * rcp_f(__expf(2.0f * x) + 1.0f);
}

// K1: per-chunk aggregate of the affine recurrence. One chunk per block,
// 128 threads, each thread owns 4 consecutive channels (float4 loads).
__global__ void k_partials(const float* __restrict__ x,
                           float* __restrict__ agg_a,
                           float* __restrict__ agg_kv,
                           int C, int Tc) {
    const int c = blockIdx.x;
    const int b = blockIdx.y;
    const int d = threadIdx.x << 2;                      // channel base
    const float* xb = x + ((size_t)b * T_ + (size_t)c * Tc) * ROW_;

    float A[4]  = {1.f, 1.f, 1.f, 1.f};
    float KV[4] = {0.f, 0.f, 0.f, 0.f};
#pragma unroll 8
    for (int i = 0; i < Tc; ++i) {
        const float* r = xb + (size_t)i * ROW_;
        const f32x4 xi = *(const f32x4*)(r + d);
        const f32x4 gi = *(const f32x4*)(r + DH_ + d);
#pragma unroll
        for (int j = 0; j < 4; ++j) {
            const float s  = sigmoid_f(gi[j]);
            const float f  = 1.0f - s;
            const float iv = tanh_f(xi[j]) * s;
            A[j]  = f * A[j];
            KV[j] = fmaf(f, KV[j], iv);
        }
    }
    const size_t idx = ((size_t)b * C + c) * DH_ + d;
    f32x4 Av  = {A[0],  A[1],  A[2],  A[3]};
    f32x4 KVv = {KV[0], KV[1], KV[2], KV[3]};
    *(f32x4*)(agg_a + idx)  = Av;
    *(f32x4*)(agg_kv + idx) = KVv;
}

// KS: exclusive scan over chunk aggregates. h0[c] = state entering chunk c.
// Grid (B), block 128 (vec4 channels). Linear in C.
__global__ void k_scan(const float* __restrict__ agg_a,
                       const float* __restrict__ agg_kv,
                       float* __restrict__ h0,
                       int C) {
    const int b = blockIdx.x;
    const int d = threadIdx.x << 2;
    float h[4] = {0.f, 0.f, 0.f, 0.f};
#pragma unroll 8
    for (int c = 0; c < C; ++c) {
        const size_t idx = ((size_t)b * C + c) * DH_ + d;
        f32x4 hv = {h[0], h[1], h[2], h[3]};
        *(f32x4*)(h0 + idx) = hv;
        const f32x4 a  = *(const f32x4*)(agg_a + idx);
        const f32x4 kv = *(const f32x4*)(agg_kv + idx);
#pragma unroll
        for (int j = 0; j < 4; ++j) h[j] = fmaf(a[j], h[j], kv[j]);
    }
}

// K2: seed from h0, recompute chunk, write gated output.
__global__ void k_apply(const float* __restrict__ x,
                        const float* __restrict__ h0buf,
                        float* __restrict__ out,
                        int C, int Tc) {
    const int c = blockIdx.x;
    const int b = blockIdx.y;
    const int d = threadIdx.x << 2;

    float h[4] = {0.f, 0.f, 0.f, 0.f};
    if (h0buf) {
        const f32x4 hv = *(const f32x4*)(h0buf + ((size_t)b * C + c) * DH_ + d);
#pragma unroll
        for (int j = 0; j < 4; ++j) h[j] = hv[j];
    }

    const float* xb = x + ((size_t)b * T_ + (size_t)c * Tc) * ROW_;
    float* ob = out + ((size_t)b * T_ + (size_t)c * Tc) * DH_;

#pragma unroll 4
    for (int i = 0; i < Tc; ++i) {
        const float* r = xb + (size_t)i * ROW_;
        const f32x4 xi = *(const f32x4*)(r + d);
        const f32x4 gi = *(const f32x4*)(r + DH_ + d);
        const f32x4 go = *(const f32x4*)(r + 2 * DH_ + d);
        f32x4 o;
#pragma unroll
        for (int j = 0; j < 4; ++j) {
            const float s  = sigmoid_f(gi[j]);
            const float f  = 1.0f - s;
            const float iv = tanh_f(xi[j]) * s;
            h[j] = fmaf(f, h[j], iv);
            o[j] = tanh_f(h[j]) * sigmoid_f(go[j]);
        }
        // out is never re-read: nontemporal store keeps x resident in L3
        // so K2's re-read of xi/gi hits cache instead of HBM.
        __builtin_nontemporal_store(o, (f32x4*)(ob + (size_t)i * DH_ + d));
    }
}

extern "C" void kernel_launch(void* const* d_in, const int* in_sizes, int n_in,
                              void* d_out, int out_size, void* d_ws, size_t ws_size,
                              hipStream_t stream) {
    const float* x = (const float*)d_in[0];
    float* out = (float*)d_out;

    const dim3 blk(DH_ / 4);   // 128 threads, 4 channels each

    // Pick chunk count C (power of two dividing T) so 3 aggregate arrays fit ws.
    int C = 256;               // Tc = 32; needs 6 MiB ws
    while (C > 1 && (size_t)B_ * C * DH_ * 3 * sizeof(float) > ws_size) C >>= 1;

    if (C == 1) {
        // No usable workspace: single sequential pass per channel (slow, correct).
        hipLaunchKernelGGL(k_apply, dim3(1, B_), blk, 0, stream,
                           x, (const float*)nullptr, out, 1, T_);
        return;
    }

    const int Tc = T_ / C;
    float* agg_a  = (float*)d_ws;
    float* agg_kv = agg_a  + (size_t)B_ * C * DH_;
    float* h0     = agg_kv + (size_t)B_ * C * DH_;

    const dim3 grid(C, B_);
    hipLaunchKernelGGL(k_partials, grid, blk, 0, stream, x, agg_a, agg_kv, C, Tc);
    hipLaunchKernelGGL(k_scan, dim3(B_), blk, 0, stream, agg_a, agg_kv, h0, C);
    hipLaunchKernelGGL(k_apply, grid, blk, 0, stream, x, h0, out, C, Tc);
}